// Round 1
// baseline (10759.241 us; speedup 1.0000x reference)
//
#include <hip/hip_runtime.h>
#include <cstdint>

typedef __attribute__((ext_vector_type(8))) short bf16x8;
typedef __attribute__((ext_vector_type(4))) float f32x4;

__device__ __forceinline__ float bf2f(unsigned short u) {
  union { unsigned int i; float f; } v;
  v.i = ((unsigned int)u) << 16;
  return v.f;
}
__device__ __forceinline__ unsigned short f2bf(float f) {
  union { float f; unsigned int i; } v;
  v.f = f;
  unsigned int x = v.i;
  return (unsigned short)((x + 0x7FFFu + ((x >> 16) & 1u)) >> 16);
}

struct StepParams {
  const int* tgt;
  const int* mask;
  const float* embedding;
  const float* enc;
  const float* Wa;
  const float* hidden;
  const float* w_ih0; const float* w_hh0; const float* b_ih0; const float* b_hh0;
  const float* w_ih1; const float* w_hh1; const float* b_ih1; const float* b_hh1;
  float* h0buf;              // [2][32][512] ping-pong
  float* h1buf;              // [2][32][512] ping-pong
  float* x0b;                // [32][1536]
  unsigned short* encb;      // [32][128][1024] bf16
  unsigned short* encwt;     // [32][128][512] bf16  (TRANSPOSED: [b][s][h])
  unsigned short* states;    // [2048][1536] bf16
  unsigned int* bars;        // one counter per barrier instance, pre-zeroed
};

// Device-scope grid barrier. One fresh counter per instance -> no reset/ABA races.
// __threadfence() at agent scope does the gfx950 wbl2/inv dance so non-atomic
// stores are visible across XCDs (Guideline 16).
__device__ __forceinline__ void gbar(unsigned int* c) {
  __syncthreads();
  if (threadIdx.x == 0) {
    __threadfence();  // release: drain + writeback my phase's stores
    __hip_atomic_fetch_add(c, 1u, __ATOMIC_RELAXED, __HIP_MEMORY_SCOPE_AGENT);
    while (__hip_atomic_load(c, __ATOMIC_RELAXED, __HIP_MEMORY_SCOPE_AGENT) < 256u)
      __builtin_amdgcn_s_sleep(1);
    __threadfence();  // acquire: invalidate stale L1/L2 before readers proceed
  }
  __syncthreads();
}

// One GRU layer phase. Thread map identical to the verified k_gru:
// tid = kq*64 + jl*32 + b ; this wg owns features j = w*2 + jl.
__device__ __forceinline__ void gru_phase(
    const float* __restrict__ x, int xK,
    const float* __restrict__ hprev,
    const float* __restrict__ w_ih, const float* __restrict__ w_hh,
    const float* __restrict__ b_ih, const float* __restrict__ b_hh,
    float* __restrict__ hout, unsigned short* states, int srow,
    int w, int tid, float* xsh, float* red) {
  int b = tid & 31;
  int jl = (tid >> 5) & 1;
  int kq = tid >> 6;
  int j = w * 2 + jl;
  int kb = kq * 64;
  float gr = 0.f, gz = 0.f, gin = 0.f, ghn = 0.f;
  for (int t0 = 0; t0 < xK; t0 += 256) {
    __syncthreads();
#pragma unroll
    for (int u = 0; u < 32; u++)
      xsh[u * 257 + tid] = x[u * xK + t0 + tid];
    __syncthreads();
    const float4* w0p = (const float4*)(w_ih + (size_t)j * xK + t0 + kb);
    const float4* w1p = (const float4*)(w_ih + (size_t)(j + 512) * xK + t0 + kb);
    const float4* w2p = (const float4*)(w_ih + (size_t)(j + 1024) * xK + t0 + kb);
    const float* xr = xsh + b * 257 + kb;
#pragma unroll 4
    for (int k4 = 0; k4 < 16; k4++) {
      float4 wa = w0p[k4], wb = w1p[k4], wc = w2p[k4];
      float xv0 = xr[k4 * 4 + 0], xv1 = xr[k4 * 4 + 1];
      float xv2 = xr[k4 * 4 + 2], xv3 = xr[k4 * 4 + 3];
      gr = fmaf(wa.x, xv0, gr); gr = fmaf(wa.y, xv1, gr);
      gr = fmaf(wa.z, xv2, gr); gr = fmaf(wa.w, xv3, gr);
      gz = fmaf(wb.x, xv0, gz); gz = fmaf(wb.y, xv1, gz);
      gz = fmaf(wb.z, xv2, gz); gz = fmaf(wb.w, xv3, gz);
      gin = fmaf(wc.x, xv0, gin); gin = fmaf(wc.y, xv1, gin);
      gin = fmaf(wc.z, xv2, gin); gin = fmaf(wc.w, xv3, gin);
    }
  }
  for (int t0 = 0; t0 < 512; t0 += 256) {
    __syncthreads();
#pragma unroll
    for (int u = 0; u < 32; u++)
      xsh[u * 257 + tid] = hprev[u * 512 + t0 + tid];
    __syncthreads();
    const float4* w0p = (const float4*)(w_hh + (size_t)j * 512 + t0 + kb);
    const float4* w1p = (const float4*)(w_hh + (size_t)(j + 512) * 512 + t0 + kb);
    const float4* w2p = (const float4*)(w_hh + (size_t)(j + 1024) * 512 + t0 + kb);
    const float* xr = xsh + b * 257 + kb;
#pragma unroll 4
    for (int k4 = 0; k4 < 16; k4++) {
      float4 wa = w0p[k4], wb = w1p[k4], wc = w2p[k4];
      float xv0 = xr[k4 * 4 + 0], xv1 = xr[k4 * 4 + 1];
      float xv2 = xr[k4 * 4 + 2], xv3 = xr[k4 * 4 + 3];
      gr = fmaf(wa.x, xv0, gr); gr = fmaf(wa.y, xv1, gr);
      gr = fmaf(wa.z, xv2, gr); gr = fmaf(wa.w, xv3, gr);
      gz = fmaf(wb.x, xv0, gz); gz = fmaf(wb.y, xv1, gz);
      gz = fmaf(wb.z, xv2, gz); gz = fmaf(wb.w, xv3, gz);
      ghn = fmaf(wc.x, xv0, ghn); ghn = fmaf(wc.y, xv1, ghn);
      ghn = fmaf(wc.z, xv2, ghn); ghn = fmaf(wc.w, xv3, ghn);
    }
  }
  red[tid * 4 + 0] = gr;
  red[tid * 4 + 1] = gz;
  red[tid * 4 + 2] = gin;
  red[tid * 4 + 3] = ghn;
  __syncthreads();
  if (tid < 64) {
#pragma unroll
    for (int g = 1; g < 4; g++) {
      gr += red[(tid + g * 64) * 4 + 0];
      gz += red[(tid + g * 64) * 4 + 1];
      gin += red[(tid + g * 64) * 4 + 2];
      ghn += red[(tid + g * 64) * 4 + 3];
    }
    gr += b_ih[j] + b_hh[j];
    gz += b_ih[j + 512] + b_hh[j + 512];
    gin += b_ih[j + 1024];
    ghn += b_hh[j + 1024];
    float r = 1.f / (1.f + __expf(-gr));
    float zz = 1.f / (1.f + __expf(-gz));
    float nv = gin + r * ghn;
    float e2 = __expf(-2.f * fabsf(nv));
    float th = (1.f - e2) / (1.f + e2);
    th = copysignf(th, nv);
    float hp = hprev[b * 512 + j];
    float hn = (1.f - zz) * th + zz * hp;
    hout[b * 512 + j] = hn;
    if (states) states[(size_t)(srow + b) * 1536 + j] = f2bf(hn);
  }
}

// Persistent kernel: prologue + all 63 decode steps in ONE launch.
// grid=256 (1 wg/CU, 4x resource slack -> co-residency guaranteed), 256 threads.
__global__ __launch_bounds__(256, 1) void k_steps(StepParams p) {
  __shared__ float xsh[32 * 257];  // 32.9 KB: gru x-stage; reused as encwt esh
  __shared__ float red[1024];
  __shared__ float h1sh[512];
  __shared__ float ssh[128];
  __shared__ float red2[128];
  int tid = threadIdx.x;
  int w = blockIdx.x;

  // ---------------- prologue (was k_init_h / k_cvt_enc / k_encwt) -----------
  {
    int idx = w * 256 + tid;
    if (idx < 16384) p.h0buf[idx] = p.hidden[idx];
    else if (idx < 32768) p.h1buf[idx - 16384] = p.hidden[idx];
    // enc -> bf16 (1M float4s over 65536 threads)
    for (int r = 0; r < 16; r++) {
      size_t i4 = (size_t)r * 65536 + idx;
      float4 v = *(const float4*)(p.enc + i4 * 4);
      ushort4 o;
      o.x = f2bf(v.x); o.y = f2bf(v.y); o.z = f2bf(v.z); o.w = f2bf(v.w);
      *(ushort4*)(p.encb + i4 * 4) = o;
    }
    // encwt (TRANSPOSED [b][s][h]): this wg does virtual blocks w and w+256
    for (int blk = w; blk < 512; blk += 256) {
      int b = blk >> 4, s0 = (blk & 15) * 8;
      __syncthreads();
      for (int u = 0; u < 32; u++) {
        int f = u * 256 + tid;
        xsh[f] = p.enc[((size_t)b * 128 + s0 + (f >> 10)) * 1024 + (f & 1023)];
      }
      __syncthreads();
      float acc0[8] = {}, acc1[8] = {};
      for (int e = 0; e < 1024; e++) {
        float w0 = p.Wa[e * 512 + tid];
        float w1 = p.Wa[e * 512 + tid + 256];
#pragma unroll
        for (int si = 0; si < 8; si++) {
          float ev = xsh[si * 1024 + e];
          acc0[si] += w0 * ev;
          acc1[si] += w1 * ev;
        }
      }
#pragma unroll
      for (int si = 0; si < 8; si++) {
        p.encwt[((size_t)b * 128 + s0 + si) * 512 + tid] = f2bf(acc0[si]);
        p.encwt[((size_t)b * 128 + s0 + si) * 512 + tid + 256] = f2bf(acc1[si]);
      }
    }
  }
  unsigned int* bar = p.bars;
  gbar(bar++);

  int ab = w >> 3, ec = w & 7;  // attention roles: batch ab, e/emb-chunk ec
  for (int t = 0; t < 63; t++) {
    int rd = t & 1, wr = rd ^ 1;
    const float* h1prev = p.h1buf + rd * 16384;
    // ---------------- Phase A: attention ----------------
    h1sh[tid] = h1prev[ab * 512 + tid];
    h1sh[tid + 256] = h1prev[ab * 512 + tid + 256];
    __syncthreads();
    {  // scores: 2 threads per s (h halves), bf16x8 loads from transposed encwt
      int s = tid & 127, part = tid >> 7;
      const unsigned short* ew = p.encwt + ((size_t)ab * 128 + s) * 512 + part * 256;
      const float* hh = h1sh + part * 256;
      float pacc = 0.f;
#pragma unroll 8
      for (int hc = 0; hc < 32; hc++) {
        bf16x8 v = *(const bf16x8*)(ew + hc * 8);
        const float* h8 = hh + hc * 8;
        pacc += bf2f((unsigned short)v[0]) * h8[0] + bf2f((unsigned short)v[1]) * h8[1]
              + bf2f((unsigned short)v[2]) * h8[2] + bf2f((unsigned short)v[3]) * h8[3]
              + bf2f((unsigned short)v[4]) * h8[4] + bf2f((unsigned short)v[5]) * h8[5]
              + bf2f((unsigned short)v[6]) * h8[6] + bf2f((unsigned short)v[7]) * h8[7];
      }
      red[tid] = pacc;
    }
    __syncthreads();
    if (tid < 128) {
      float sc = (red[tid] + red[tid + 128]) * 0.03125f;  // 1/sqrt(1024)
      if (p.mask[ab * 128 + tid] == 0) sc = -__builtin_huge_valf();
      ssh[tid] = sc;
      red2[tid] = sc;
    }
    __syncthreads();
    for (int st = 64; st > 0; st >>= 1) {
      if (tid < st) red2[tid] = fmaxf(red2[tid], red2[tid + st]);
      __syncthreads();
    }
    float mx = red2[0];
    __syncthreads();
    if (tid < 128) {
      float e = __expf(ssh[tid] - mx);
      ssh[tid] = e;
      red2[tid] = e;
    }
    __syncthreads();
    for (int st = 64; st > 0; st >>= 1) {
      if (tid < st) red2[tid] += red2[tid + st];
      __syncthreads();
    }
    float inv = 1.f / red2[0];
    __syncthreads();
    if (tid < 128) ssh[tid] *= inv;
    __syncthreads();
    {  // ctx for this wg's 128-wide e-chunk (2 threads per e, s halves)
      int el = tid & 127, sh_ = tid >> 7;
      const unsigned short* eb = p.encb + (size_t)ab * 131072 + ec * 128 + el;
      int sbase = sh_ * 64;
      float c = 0.f;
#pragma unroll 8
      for (int s2 = 0; s2 < 64; s2++)
        c += ssh[sbase + s2] * bf2f(eb[(size_t)(sbase + s2) * 1024]);
      red[tid] = c;
    }
    __syncthreads();
    if (tid < 128) {
      float cv = red[tid] + red[tid + 128];
      p.x0b[ab * 1536 + 512 + ec * 128 + tid] = cv;
      p.states[(size_t)(t * 32 + ab) * 1536 + 512 + ec * 128 + tid] = f2bf(cv);
    }
    {  // embedding gather: this wg's 64-wide chunk
      int tok = p.tgt[ab * 64 + t];
      if (tid < 64)
        p.x0b[ab * 1536 + ec * 64 + tid] = p.embedding[(size_t)tok * 512 + ec * 64 + tid];
    }
    gbar(bar++);
    // ---------------- Phase B: GRU layer 0 ----------------
    gru_phase(p.x0b, 1536, p.h0buf + rd * 16384, p.w_ih0, p.w_hh0, p.b_ih0, p.b_hh0,
              p.h0buf + wr * 16384, (unsigned short*)nullptr, 0, w, tid, xsh, red);
    gbar(bar++);
    // ---------------- Phase C: GRU layer 1 ----------------
    gru_phase(p.h0buf + wr * 16384, 512, p.h1buf + rd * 16384, p.w_ih1, p.w_hh1,
              p.b_ih1, p.b_hh1, p.h1buf + wr * 16384, p.states, t * 32, w, tid, xsh, red);
    gbar(bar++);
  }
}

// ---------------- batched logits GEMM: [2016x1536] @ fc_w.T [1536x32000] ----
// XCD-swizzled: the 16 m-blocks sharing one B-panel land on one XCD's L2.
__global__ __launch_bounds__(256) void k_gemm(
    const unsigned short* __restrict__ states,  // [2048][1536] bf16
    const float* __restrict__ fc_w,             // [32000][1536]
    const float* __restrict__ fc_b,             // [32000]
    float* __restrict__ out) {                  // [32][63][32000]
  __shared__ unsigned short Ash[128 * 40];
  __shared__ unsigned short Bsh[128 * 40];
  int tid = threadIdx.x;
  int bx = blockIdx.x;
  int bid = (bx & 7) * 500 + (bx >> 3);  // 4000 = 8 XCDs * 500, bijective
  int m0 = (bid & 15) * 128;
  int n0 = (bid >> 4) * 128;
  int lane = tid & 63, wave = tid >> 6;
  int q = lane >> 4, l16 = lane & 15;
  int wrow = (wave >> 1) * 64, wcol = (wave & 1) * 64;
  int arow = tid >> 1, ahalf = tid & 1;
  f32x4 acc[4][4] = {};
  const unsigned short* ag = states + (size_t)(m0 + arow) * 1536 + ahalf * 16;
  const float* bg = fc_w + (size_t)(n0 + arow) * 1536 + ahalf * 16;
  for (int k0 = 0; k0 < 1536; k0 += 32) {
    {  // stage A (already bf16)
      const int4* src = (const int4*)(ag + k0);
      int4* dst = (int4*)(Ash + arow * 40 + ahalf * 16);
      dst[0] = src[0];
      dst[1] = src[1];
    }
    {  // stage B (fp32 -> bf16)
      const float4* src = (const float4*)(bg + k0);
      __align__(16) unsigned short us[16];
#pragma unroll
      for (int i = 0; i < 4; i++) {
        float4 v = src[i];
        us[i * 4 + 0] = f2bf(v.x);
        us[i * 4 + 1] = f2bf(v.y);
        us[i * 4 + 2] = f2bf(v.z);
        us[i * 4 + 3] = f2bf(v.w);
      }
      int4* dst = (int4*)(Bsh + arow * 40 + ahalf * 16);
      dst[0] = ((int4*)us)[0];
      dst[1] = ((int4*)us)[1];
    }
    __syncthreads();
    bf16x8 av[4], bv[4];
#pragma unroll
    for (int i = 0; i < 4; i++) {
      av[i] = *(const bf16x8*)(Ash + (wrow + i * 16 + l16) * 40 + q * 8);
      bv[i] = *(const bf16x8*)(Bsh + (wcol + i * 16 + l16) * 40 + q * 8);
    }
#pragma unroll
    for (int mi = 0; mi < 4; mi++)
#pragma unroll
      for (int ni = 0; ni < 4; ni++)
        acc[mi][ni] = __builtin_amdgcn_mfma_f32_16x16x32_bf16(av[mi], bv[ni], acc[mi][ni], 0, 0, 0);
    __syncthreads();
  }
  float fb[4];
#pragma unroll
  for (int ni = 0; ni < 4; ni++) fb[ni] = fc_b[n0 + wcol + ni * 16 + l16];
#pragma unroll
  for (int mi = 0; mi < 4; mi++) {
#pragma unroll
    for (int r = 0; r < 4; r++) {
      int grow = m0 + wrow + mi * 16 + q * 4 + r;
      if (grow < 2016) {
        int tt = grow >> 5, bb = grow & 31;
        float* op = out + (size_t)bb * 2016000 + (size_t)tt * 32000 + n0 + wcol;
#pragma unroll
        for (int ni = 0; ni < 4; ni++)
          op[ni * 16 + l16] = acc[mi][ni][r] + fb[ni];
      }
    }
  }
}

extern "C" void kernel_launch(void* const* d_in, const int* in_sizes, int n_in,
                              void* d_out, int out_size, void* d_ws, size_t ws_size,
                              hipStream_t stream) {
  const int* tgt = (const int*)d_in[0];
  const float* hidden = (const float*)d_in[1];
  const float* enc = (const float*)d_in[2];
  const int* mask = (const int*)d_in[3];
  const float* embedding = (const float*)d_in[4];
  const float* Wa = (const float*)d_in[5];
  const float* w_ih0 = (const float*)d_in[6];
  const float* w_hh0 = (const float*)d_in[7];
  const float* b_ih0 = (const float*)d_in[8];
  const float* b_hh0 = (const float*)d_in[9];
  const float* w_ih1 = (const float*)d_in[10];
  const float* w_hh1 = (const float*)d_in[11];
  const float* b_ih1 = (const float*)d_in[12];
  const float* b_hh1 = (const float*)d_in[13];
  const float* fc_w = (const float*)d_in[14];
  const float* fc_b = (const float*)d_in[15];
  float* out = (float*)d_out;
  char* ws = (char*)d_ws;

  float* h0buf = (float*)(ws + 0);                           // [2][32][512] f32
  float* h1buf = (float*)(ws + 131072);                      // [2][32][512] f32
  float* x0b = (float*)(ws + 262144);                        // [32][1536] f32
  unsigned short* encb = (unsigned short*)(ws + 458752);     // [32][128][1024] bf16
  unsigned short* encwt = (unsigned short*)(ws + 8847360);   // [32][128][512] bf16
  unsigned short* states = (unsigned short*)(ws + 13041664); // [2048][1536] bf16
  // barrier counters live in the unused states rows 2016..2047 (98 KB slack);
  // k_gemm only *stages* (never emits) rows >= 2016, so tiny bf16 garbage is fine.
  unsigned int* bars = (unsigned int*)(ws + 19234816);

  hipMemsetAsync(bars, 0, 4096, stream);

  StepParams p;
  p.tgt = tgt; p.mask = mask; p.embedding = embedding; p.enc = enc; p.Wa = Wa;
  p.hidden = hidden;
  p.w_ih0 = w_ih0; p.w_hh0 = w_hh0; p.b_ih0 = b_ih0; p.b_hh0 = b_hh0;
  p.w_ih1 = w_ih1; p.w_hh1 = w_hh1; p.b_ih1 = b_ih1; p.b_hh1 = b_hh1;
  p.h0buf = h0buf; p.h1buf = h1buf; p.x0b = x0b;
  p.encb = encb; p.encwt = encwt; p.states = states; p.bars = bars;

  // 256 wg of 256 thr, ~40 KB LDS, LB(256,1): >=4 blocks/CU capacity on all
  // 256 CUs -> all wg co-resident at dispatch; grid barrier cannot deadlock.
  k_steps<<<dim3(256), dim3(256), 0, stream>>>(p);

  k_gemm<<<4000, 256, 0, stream>>>(states, fc_w, fc_b, out);
}

// Round 2
// 6466.103 us; speedup vs baseline: 1.6639x; 1.6639x over previous
//
#include <hip/hip_runtime.h>
#include <cstdint>

typedef __attribute__((ext_vector_type(8))) short bf16x8;
typedef __attribute__((ext_vector_type(4))) float f32x4;
typedef __attribute__((ext_vector_type(2))) float f32x2;

__device__ __forceinline__ float bf2f(unsigned short u) {
  union { unsigned int i; float f; } v;
  v.i = ((unsigned int)u) << 16;
  return v.f;
}
__device__ __forceinline__ unsigned short f2bf(float f) {
  union { float f; unsigned int i; } v;
  v.f = f;
  unsigned int x = v.i;
  return (unsigned short)((x + 0x7FFFu + ((x >> 16) & 1u)) >> 16);
}

struct StepParams {
  const int* tgt;
  const int* mask;
  const float* embedding;
  const float* enc;
  const float* Wa;
  const float* hidden;
  const float* w_ih0; const float* w_hh0; const float* b_ih0; const float* b_hh0;
  const float* w_ih1; const float* w_hh1; const float* b_ih1; const float* b_hh1;
  float* h0buf;              // [2][32][512] ping-pong
  float* h1buf;              // [2][32][512] ping-pong
  float* x0b;                // [32][1536]
  unsigned short* encb;      // [32][128][1024] bf16
  unsigned short* encwt;     // [32][128][512] bf16  (TRANSPOSED: [b][s][h])
  unsigned short* states;    // [2048][1536] bf16
  unsigned int* bars;        // one counter per barrier instance, pre-zeroed
};

// ---- invalidate-free grid barrier -----------------------------------------
// __syncthreads() drains every wave's stores to L2 (vmcnt(0) before s_barrier).
// Thread 0 then does an agent RELEASE fence -> buffer_wbl2 (writeback dirty L2,
// NO invalidate: clean weight/enc lines stay resident), arrives at the MALL
// counter, spins. No acquire invalidate: consumers read mutable buffers with
// sc0 sc1 (L1+L2-bypassing) loads instead.
__device__ __forceinline__ void gbar(unsigned int* c) {
  __syncthreads();
  if (threadIdx.x == 0) {
    __builtin_amdgcn_fence(__ATOMIC_RELEASE, "agent");  // waitcnt + wbl2, no inv
    __hip_atomic_fetch_add(c, 1u, __ATOMIC_RELAXED, __HIP_MEMORY_SCOPE_AGENT);
    while (__hip_atomic_load(c, __ATOMIC_RELAXED, __HIP_MEMORY_SCOPE_AGENT) < 256u)
      __builtin_amdgcn_s_sleep(1);
    // compiler-level ordering only (workgroup acquire emits no cache op)
    __hip_atomic_load(c, __ATOMIC_ACQUIRE, __HIP_MEMORY_SCOPE_WORKGROUP);
  }
  __syncthreads();
}

// Coherent (cross-XCD-fresh) staging of a 32-row x 256-col fp32 chunk into
// LDS (row stride 257). 8 dwordx4 issues per thread, ONE vmcnt wait.
__device__ __forceinline__ void stage_coh(const float* __restrict__ src, int ldk,
                                          int t0, int tid, float* xsh) {
  f32x4 st[8];
#pragma unroll
  for (int u = 0; u < 8; u++) {
    int idx = u * 256 + tid;
    int row = idx >> 6, c4 = idx & 63;
    const float* p = src + (size_t)row * ldk + t0 + c4 * 4;
    asm volatile("global_load_dwordx4 %0, %1, off sc0 sc1" : "=&v"(st[u]) : "v"(p));
  }
  asm volatile("s_waitcnt vmcnt(0)" ::: "memory");
  __builtin_amdgcn_sched_barrier(0);
#pragma unroll
  for (int u = 0; u < 8; u++) {
    int idx = u * 256 + tid;
    int row = idx >> 6, c4 = idx & 63;
    float* d = xsh + row * 257 + c4 * 4;
    d[0] = st[u][0]; d[1] = st[u][1]; d[2] = st[u][2]; d[3] = st[u][3];
  }
}

// One GRU layer phase. Thread map identical to the verified k_gru:
// tid = kq*64 + jl*32 + b ; this wg owns features j = w*2 + jl.
__device__ __forceinline__ void gru_phase(
    const float* __restrict__ x, int xK,
    const float* __restrict__ hprev,
    const float* __restrict__ w_ih, const float* __restrict__ w_hh,
    const float* __restrict__ b_ih, const float* __restrict__ b_hh,
    float* __restrict__ hout, unsigned short* states, int srow,
    int w, int tid, float* xsh, float* red) {
  int b = tid & 31;
  int jl = (tid >> 5) & 1;
  int kq = tid >> 6;
  int j = w * 2 + jl;
  int kb = kq * 64;
  float gr = 0.f, gz = 0.f, gin = 0.f, ghn = 0.f;
  for (int t0 = 0; t0 < xK; t0 += 256) {
    __syncthreads();
    stage_coh(x, xK, t0, tid, xsh);
    __syncthreads();
    const float4* w0p = (const float4*)(w_ih + (size_t)j * xK + t0 + kb);
    const float4* w1p = (const float4*)(w_ih + (size_t)(j + 512) * xK + t0 + kb);
    const float4* w2p = (const float4*)(w_ih + (size_t)(j + 1024) * xK + t0 + kb);
    const float* xr = xsh + b * 257 + kb;
#pragma unroll 4
    for (int k4 = 0; k4 < 16; k4++) {
      float4 wa = w0p[k4], wb = w1p[k4], wc = w2p[k4];
      float xv0 = xr[k4 * 4 + 0], xv1 = xr[k4 * 4 + 1];
      float xv2 = xr[k4 * 4 + 2], xv3 = xr[k4 * 4 + 3];
      gr = fmaf(wa.x, xv0, gr); gr = fmaf(wa.y, xv1, gr);
      gr = fmaf(wa.z, xv2, gr); gr = fmaf(wa.w, xv3, gr);
      gz = fmaf(wb.x, xv0, gz); gz = fmaf(wb.y, xv1, gz);
      gz = fmaf(wb.z, xv2, gz); gz = fmaf(wb.w, xv3, gz);
      gin = fmaf(wc.x, xv0, gin); gin = fmaf(wc.y, xv1, gin);
      gin = fmaf(wc.z, xv2, gin); gin = fmaf(wc.w, xv3, gin);
    }
  }
  for (int t0 = 0; t0 < 512; t0 += 256) {
    __syncthreads();
    stage_coh(hprev, 512, t0, tid, xsh);
    __syncthreads();
    const float4* w0p = (const float4*)(w_hh + (size_t)j * 512 + t0 + kb);
    const float4* w1p = (const float4*)(w_hh + (size_t)(j + 512) * 512 + t0 + kb);
    const float4* w2p = (const float4*)(w_hh + (size_t)(j + 1024) * 512 + t0 + kb);
    const float* xr = xsh + b * 257 + kb;
#pragma unroll 4
    for (int k4 = 0; k4 < 16; k4++) {
      float4 wa = w0p[k4], wb = w1p[k4], wc = w2p[k4];
      float xv0 = xr[k4 * 4 + 0], xv1 = xr[k4 * 4 + 1];
      float xv2 = xr[k4 * 4 + 2], xv3 = xr[k4 * 4 + 3];
      gr = fmaf(wa.x, xv0, gr); gr = fmaf(wa.y, xv1, gr);
      gr = fmaf(wa.z, xv2, gr); gr = fmaf(wa.w, xv3, gr);
      gz = fmaf(wb.x, xv0, gz); gz = fmaf(wb.y, xv1, gz);
      gz = fmaf(wb.z, xv2, gz); gz = fmaf(wb.w, xv3, gz);
      ghn = fmaf(wc.x, xv0, ghn); ghn = fmaf(wc.y, xv1, ghn);
      ghn = fmaf(wc.z, xv2, ghn); ghn = fmaf(wc.w, xv3, ghn);
    }
  }
  red[tid * 4 + 0] = gr;
  red[tid * 4 + 1] = gz;
  red[tid * 4 + 2] = gin;
  red[tid * 4 + 3] = ghn;
  __syncthreads();
  if (tid < 64) {
#pragma unroll
    for (int g = 1; g < 4; g++) {
      gr += red[(tid + g * 64) * 4 + 0];
      gz += red[(tid + g * 64) * 4 + 1];
      gin += red[(tid + g * 64) * 4 + 2];
      ghn += red[(tid + g * 64) * 4 + 3];
    }
    gr += b_ih[j] + b_hh[j];
    gz += b_ih[j + 512] + b_hh[j + 512];
    gin += b_ih[j + 1024];
    ghn += b_hh[j + 1024];
    float r = 1.f / (1.f + __expf(-gr));
    float zz = 1.f / (1.f + __expf(-gz));
    float nv = gin + r * ghn;
    float e2 = __expf(-2.f * fabsf(nv));
    float th = (1.f - e2) / (1.f + e2);
    th = copysignf(th, nv);
    float hp;
    asm volatile("global_load_dword %0, %1, off sc0 sc1\n\ts_waitcnt vmcnt(0)"
                 : "=&v"(hp) : "v"(hprev + b * 512 + j) : "memory");
    __builtin_amdgcn_sched_barrier(0);
    float hn = (1.f - zz) * th + zz * hp;
    hout[b * 512 + j] = hn;
    if (states) states[(size_t)(srow + b) * 1536 + j] = f2bf(hn);
  }
}

// Persistent kernel: prologue + all 63 decode steps in ONE launch.
// grid=256 (1 wg/CU, 4x resource slack -> co-residency guaranteed), 256 threads.
__global__ __launch_bounds__(256, 1) void k_steps(StepParams p) {
  __shared__ float xsh[32 * 257];  // 32.9 KB: gru x-stage; reused as encwt esh
  __shared__ float red[1024];
  __shared__ float h1sh[512];
  __shared__ float ssh[128];
  __shared__ float red2[128];
  int tid = threadIdx.x;
  int w = blockIdx.x;

  // ---------------- prologue (init h, enc->bf16, encwt) ---------------------
  {
    int idx = w * 256 + tid;
    if (idx < 16384) p.h0buf[idx] = p.hidden[idx];
    else if (idx < 32768) p.h1buf[idx - 16384] = p.hidden[idx];
    for (int r = 0; r < 16; r++) {
      size_t i4 = (size_t)r * 65536 + idx;
      float4 v = *(const float4*)(p.enc + i4 * 4);
      ushort4 o;
      o.x = f2bf(v.x); o.y = f2bf(v.y); o.z = f2bf(v.z); o.w = f2bf(v.w);
      *(ushort4*)(p.encb + i4 * 4) = o;
    }
    // encwt (TRANSPOSED [b][s][h]): this wg does virtual blocks w and w+256
    for (int blk = w; blk < 512; blk += 256) {
      int b = blk >> 4, s0 = (blk & 15) * 8;
      __syncthreads();
      for (int u = 0; u < 32; u++) {
        int f = u * 256 + tid;
        xsh[f] = p.enc[((size_t)b * 128 + s0 + (f >> 10)) * 1024 + (f & 1023)];
      }
      __syncthreads();
      float acc0[8] = {}, acc1[8] = {};
      for (int e = 0; e < 1024; e++) {
        float w0 = p.Wa[e * 512 + tid];
        float w1 = p.Wa[e * 512 + tid + 256];
#pragma unroll
        for (int si = 0; si < 8; si++) {
          float ev = xsh[si * 1024 + e];
          acc0[si] += w0 * ev;
          acc1[si] += w1 * ev;
        }
      }
#pragma unroll
      for (int si = 0; si < 8; si++) {
        p.encwt[((size_t)b * 128 + s0 + si) * 512 + tid] = f2bf(acc0[si]);
        p.encwt[((size_t)b * 128 + s0 + si) * 512 + tid + 256] = f2bf(acc1[si]);
      }
    }
  }
  unsigned int* bar = p.bars;
  gbar(bar++);

  int ab = w >> 3, ec = w & 7;  // attention roles: batch ab, e/emb-chunk ec
  for (int t = 0; t < 63; t++) {
    int rd = t & 1, wr = rd ^ 1;
    const float* h1prev = p.h1buf + rd * 16384;
    // ---------------- Phase A: attention ----------------
    {  // coherent h1 stage: 1 dwordx2 per thread, one wait
      f32x2 hv;
      const float* hp2 = h1prev + ab * 512 + tid * 2;
      asm volatile("global_load_dwordx2 %0, %1, off sc0 sc1" : "=&v"(hv) : "v"(hp2));
      asm volatile("s_waitcnt vmcnt(0)" ::: "memory");
      __builtin_amdgcn_sched_barrier(0);
      h1sh[tid * 2] = hv[0];
      h1sh[tid * 2 + 1] = hv[1];
    }
    __syncthreads();
    {  // scores: 2 threads per s (h halves), bf16x8 loads from transposed encwt
      int s = tid & 127, part = tid >> 7;
      const unsigned short* ew = p.encwt + ((size_t)ab * 128 + s) * 512 + part * 256;
      const float* hh = h1sh + part * 256;
      float pacc = 0.f;
#pragma unroll 8
      for (int hc = 0; hc < 32; hc++) {
        bf16x8 v = *(const bf16x8*)(ew + hc * 8);
        const float* h8 = hh + hc * 8;
        pacc += bf2f((unsigned short)v[0]) * h8[0] + bf2f((unsigned short)v[1]) * h8[1]
              + bf2f((unsigned short)v[2]) * h8[2] + bf2f((unsigned short)v[3]) * h8[3]
              + bf2f((unsigned short)v[4]) * h8[4] + bf2f((unsigned short)v[5]) * h8[5]
              + bf2f((unsigned short)v[6]) * h8[6] + bf2f((unsigned short)v[7]) * h8[7];
      }
      red[tid] = pacc;
    }
    __syncthreads();
    if (tid < 128) {
      float sc = (red[tid] + red[tid + 128]) * 0.03125f;  // 1/sqrt(1024)
      if (p.mask[ab * 128 + tid] == 0) sc = -__builtin_huge_valf();
      ssh[tid] = sc;
      red2[tid] = sc;
    }
    __syncthreads();
    for (int st = 64; st > 0; st >>= 1) {
      if (tid < st) red2[tid] = fmaxf(red2[tid], red2[tid + st]);
      __syncthreads();
    }
    float mx = red2[0];
    __syncthreads();
    if (tid < 128) {
      float e = __expf(ssh[tid] - mx);
      ssh[tid] = e;
      red2[tid] = e;
    }
    __syncthreads();
    for (int st = 64; st > 0; st >>= 1) {
      if (tid < st) red2[tid] += red2[tid + st];
      __syncthreads();
    }
    float inv = 1.f / red2[0];
    __syncthreads();
    if (tid < 128) ssh[tid] *= inv;
    __syncthreads();
    {  // ctx for this wg's 128-wide e-chunk (2 threads per e, s halves)
      int el = tid & 127, sh_ = tid >> 7;
      const unsigned short* eb = p.encb + (size_t)ab * 131072 + ec * 128 + el;
      int sbase = sh_ * 64;
      float c = 0.f;
#pragma unroll 8
      for (int s2 = 0; s2 < 64; s2++)
        c += ssh[sbase + s2] * bf2f(eb[(size_t)(sbase + s2) * 1024]);
      red[tid] = c;
    }
    __syncthreads();
    if (tid < 128) {
      float cv = red[tid] + red[tid + 128];
      p.x0b[ab * 1536 + 512 + ec * 128 + tid] = cv;
      p.states[(size_t)(t * 32 + ab) * 1536 + 512 + ec * 128 + tid] = f2bf(cv);
    }
    {  // embedding gather: this wg's 64-wide chunk
      int tok = p.tgt[ab * 64 + t];
      if (tid < 64)
        p.x0b[ab * 1536 + ec * 64 + tid] = p.embedding[(size_t)tok * 512 + ec * 64 + tid];
    }
    gbar(bar++);
    // ---------------- Phase B: GRU layer 0 ----------------
    gru_phase(p.x0b, 1536, p.h0buf + rd * 16384, p.w_ih0, p.w_hh0, p.b_ih0, p.b_hh0,
              p.h0buf + wr * 16384, (unsigned short*)nullptr, 0, w, tid, xsh, red);
    gbar(bar++);
    // ---------------- Phase C: GRU layer 1 ----------------
    gru_phase(p.h0buf + wr * 16384, 512, p.h1buf + rd * 16384, p.w_ih1, p.w_hh1,
              p.b_ih1, p.b_hh1, p.h1buf + wr * 16384, p.states, t * 32, w, tid, xsh, red);
    gbar(bar++);
  }
}

// ---------------- batched logits GEMM: [2016x1536] @ fc_w.T [1536x32000] ----
// XCD-swizzled: the 16 m-blocks sharing one B-panel land on one XCD's L2.
__global__ __launch_bounds__(256) void k_gemm(
    const unsigned short* __restrict__ states,  // [2048][1536] bf16
    const float* __restrict__ fc_w,             // [32000][1536]
    const float* __restrict__ fc_b,             // [32000]
    float* __restrict__ out) {                  // [32][63][32000]
  __shared__ unsigned short Ash[128 * 40];
  __shared__ unsigned short Bsh[128 * 40];
  int tid = threadIdx.x;
  int bx = blockIdx.x;
  int bid = (bx & 7) * 500 + (bx >> 3);  // 4000 = 8 XCDs * 500, bijective
  int m0 = (bid & 15) * 128;
  int n0 = (bid >> 4) * 128;
  int lane = tid & 63, wave = tid >> 6;
  int q = lane >> 4, l16 = lane & 15;
  int wrow = (wave >> 1) * 64, wcol = (wave & 1) * 64;
  int arow = tid >> 1, ahalf = tid & 1;
  f32x4 acc[4][4] = {};
  const unsigned short* ag = states + (size_t)(m0 + arow) * 1536 + ahalf * 16;
  const float* bg = fc_w + (size_t)(n0 + arow) * 1536 + ahalf * 16;
  for (int k0 = 0; k0 < 1536; k0 += 32) {
    {  // stage A (already bf16)
      const int4* src = (const int4*)(ag + k0);
      int4* dst = (int4*)(Ash + arow * 40 + ahalf * 16);
      dst[0] = src[0];
      dst[1] = src[1];
    }
    {  // stage B (fp32 -> bf16)
      const float4* src = (const float4*)(bg + k0);
      __align__(16) unsigned short us[16];
#pragma unroll
      for (int i = 0; i < 4; i++) {
        float4 v = src[i];
        us[i * 4 + 0] = f2bf(v.x);
        us[i * 4 + 1] = f2bf(v.y);
        us[i * 4 + 2] = f2bf(v.z);
        us[i * 4 + 3] = f2bf(v.w);
      }
      int4* dst = (int4*)(Bsh + arow * 40 + ahalf * 16);
      dst[0] = ((int4*)us)[0];
      dst[1] = ((int4*)us)[1];
    }
    __syncthreads();
    bf16x8 av[4], bv[4];
#pragma unroll
    for (int i = 0; i < 4; i++) {
      av[i] = *(const bf16x8*)(Ash + (wrow + i * 16 + l16) * 40 + q * 8);
      bv[i] = *(const bf16x8*)(Bsh + (wcol + i * 16 + l16) * 40 + q * 8);
    }
#pragma unroll
    for (int mi = 0; mi < 4; mi++)
#pragma unroll
      for (int ni = 0; ni < 4; ni++)
        acc[mi][ni] = __builtin_amdgcn_mfma_f32_16x16x32_bf16(av[mi], bv[ni], acc[mi][ni], 0, 0, 0);
    __syncthreads();
  }
  float fb[4];
#pragma unroll
  for (int ni = 0; ni < 4; ni++) fb[ni] = fc_b[n0 + wcol + ni * 16 + l16];
#pragma unroll
  for (int mi = 0; mi < 4; mi++) {
#pragma unroll
    for (int r = 0; r < 4; r++) {
      int grow = m0 + wrow + mi * 16 + q * 4 + r;
      if (grow < 2016) {
        int tt = grow >> 5, bb = grow & 31;
        float* op = out + (size_t)bb * 2016000 + (size_t)tt * 32000 + n0 + wcol;
#pragma unroll
        for (int ni = 0; ni < 4; ni++)
          op[ni * 16 + l16] = acc[mi][ni][r] + fb[ni];
      }
    }
  }
}

extern "C" void kernel_launch(void* const* d_in, const int* in_sizes, int n_in,
                              void* d_out, int out_size, void* d_ws, size_t ws_size,
                              hipStream_t stream) {
  const int* tgt = (const int*)d_in[0];
  const float* hidden = (const float*)d_in[1];
  const float* enc = (const float*)d_in[2];
  const int* mask = (const int*)d_in[3];
  const float* embedding = (const float*)d_in[4];
  const float* Wa = (const float*)d_in[5];
  const float* w_ih0 = (const float*)d_in[6];
  const float* w_hh0 = (const float*)d_in[7];
  const float* b_ih0 = (const float*)d_in[8];
  const float* b_hh0 = (const float*)d_in[9];
  const float* w_ih1 = (const float*)d_in[10];
  const float* w_hh1 = (const float*)d_in[11];
  const float* b_ih1 = (const float*)d_in[12];
  const float* b_hh1 = (const float*)d_in[13];
  const float* fc_w = (const float*)d_in[14];
  const float* fc_b = (const float*)d_in[15];
  float* out = (float*)d_out;
  char* ws = (char*)d_ws;

  float* h0buf = (float*)(ws + 0);                           // [2][32][512] f32
  float* h1buf = (float*)(ws + 131072);                      // [2][32][512] f32
  float* x0b = (float*)(ws + 262144);                        // [32][1536] f32
  unsigned short* encb = (unsigned short*)(ws + 458752);     // [32][128][1024] bf16
  unsigned short* encwt = (unsigned short*)(ws + 8847360);   // [32][128][512] bf16
  unsigned short* states = (unsigned short*)(ws + 13041664); // [2048][1536] bf16
  unsigned int* bars = (unsigned int*)(ws + 19234816);       // 190 counters

  hipMemsetAsync(bars, 0, 4096, stream);

  StepParams p;
  p.tgt = tgt; p.mask = mask; p.embedding = embedding; p.enc = enc; p.Wa = Wa;
  p.hidden = hidden;
  p.w_ih0 = w_ih0; p.w_hh0 = w_hh0; p.b_ih0 = b_ih0; p.b_hh0 = b_hh0;
  p.w_ih1 = w_ih1; p.w_hh1 = w_hh1; p.b_ih1 = b_ih1; p.b_hh1 = b_hh1;
  p.h0buf = h0buf; p.h1buf = h1buf; p.x0b = x0b;
  p.encb = encb; p.encwt = encwt; p.states = states; p.bars = bars;

  k_steps<<<dim3(256), dim3(256), 0, stream>>>(p);

  k_gemm<<<4000, 256, 0, stream>>>(states, fc_w, fc_b, out);
}

// Round 3
// 5196.411 us; speedup vs baseline: 2.0705x; 1.2443x over previous
//
#include <hip/hip_runtime.h>
#include <cstdint>

typedef __attribute__((ext_vector_type(8))) short bf16x8;
typedef __attribute__((ext_vector_type(4))) float f32x4;
typedef __attribute__((ext_vector_type(2))) int i32x2;

__device__ __forceinline__ float bf2f(unsigned short u) {
  union { unsigned int i; float f; } v;
  v.i = ((unsigned int)u) << 16;
  return v.f;
}
__device__ __forceinline__ unsigned short f2bf(float f) {
  union { float f; unsigned int i; } v;
  v.f = f;
  unsigned int x = v.i;
  return (unsigned short)((x + 0x7FFFu + ((x >> 16) & 1u)) >> 16);
}

// ---- coherent (write-through to MALL) stores for cross-XCD mutable data ----
__device__ __forceinline__ void st_f32_coh(float* p, float v) {
  asm volatile("global_store_dword %0, %1, off sc0 sc1" :: "v"(p), "v"(v) : "memory");
}
__device__ __forceinline__ void st_u16_coh(unsigned short* p, unsigned int v) {
  asm volatile("global_store_short %0, %1, off sc0 sc1" :: "v"(p), "v"(v) : "memory");
}
__device__ __forceinline__ void st_b64_coh(void* p, i32x2 v) {
  asm volatile("global_store_dwordx2 %0, %1, off sc0 sc1" :: "v"(p), "v"(v) : "memory");
}

struct StepParams {
  const int* tgt;
  const int* mask;
  const float* embedding;
  const float* enc;
  const float* Wa;
  const float* hidden;
  const float* w_ih0; const float* w_hh0; const float* b_ih0; const float* b_hh0;
  const float* w_ih1; const float* w_hh1; const float* b_ih1; const float* b_hh1;
  float* h0buf;              // [64][32][512] rotating slots
  float* h1buf;              // [64][32][512] rotating slots
  float* x0b;                // [63][32][1536] rotating slots
  unsigned short* encb;      // [32][128][1024] bf16
  unsigned short* encwt;     // [32][128][512] bf16  (TRANSPOSED: [b][s][h])
  unsigned short* states;    // [2048][1536] bf16
  unsigned int* bars;        // one counter per barrier instance, pre-zeroed
};

// Pure-atomic grid barrier: NO fences, NO cache maintenance. Correctness comes
// from (a) producers write shared mutable data with sc0sc1 write-through (data
// lands at MALL, no dirty L2 lines), (b) every mutable buffer slot is renamed
// per step, so a consumer's L1/L2 cannot hold a stale copy (first touch).
// Weights / enc tables therefore stay L2-resident for the entire kernel.
__device__ __forceinline__ void gbar(unsigned int* c) {
  asm volatile("s_waitcnt vmcnt(0)" ::: "memory");  // drain this wave's coh stores
  __syncthreads();
  if (threadIdx.x == 0) {
    __hip_atomic_fetch_add(c, 1u, __ATOMIC_RELAXED, __HIP_MEMORY_SCOPE_AGENT);
    while (__hip_atomic_load(c, __ATOMIC_RELAXED, __HIP_MEMORY_SCOPE_AGENT) < 256u)
      __builtin_amdgcn_s_sleep(1);
  }
  __syncthreads();
}

// Conflict-free LDS stage: lane-stride-1 scalar stores (banks 0..31 round-robin),
// coalesced 256B global loads. Row stride 257 keeps reader banks (b + k) % 32
// all-distinct.
__device__ __forceinline__ void stage(const float* __restrict__ src, int ldk,
                                      int t0, int tid, float* __restrict__ xsh) {
#pragma unroll
  for (int u = 0; u < 32; u++)
    xsh[u * 257 + tid] = src[(size_t)u * ldk + t0 + tid];
}

// One GRU layer phase. tid = kq*64 + jl*32 + b ; wg owns features j = w*2 + jl.
__device__ __forceinline__ void gru_phase(
    const float* __restrict__ x, int xK,
    const float* __restrict__ hprev,
    const float* __restrict__ w_ih, const float* __restrict__ w_hh,
    const float* __restrict__ b_ih, const float* __restrict__ b_hh,
    float* __restrict__ hout, unsigned short* states, int srow,
    int w, int tid, float* xsh, float* red) {
  int b = tid & 31;
  int jl = (tid >> 5) & 1;
  int kq = tid >> 6;
  int j = w * 2 + jl;
  int kb = kq * 64;
  float gr = 0.f, gz = 0.f, gin = 0.f, ghn = 0.f;
  for (int t0 = 0; t0 < xK; t0 += 256) {
    __syncthreads();
    stage(x, xK, t0, tid, xsh);
    __syncthreads();
    const float4* w0p = (const float4*)(w_ih + (size_t)j * xK + t0 + kb);
    const float4* w1p = (const float4*)(w_ih + (size_t)(j + 512) * xK + t0 + kb);
    const float4* w2p = (const float4*)(w_ih + (size_t)(j + 1024) * xK + t0 + kb);
    const float* xr = xsh + b * 257 + kb;
#pragma unroll 4
    for (int k4 = 0; k4 < 16; k4++) {
      float4 wa = w0p[k4], wb = w1p[k4], wc = w2p[k4];
      float xv0 = xr[k4 * 4 + 0], xv1 = xr[k4 * 4 + 1];
      float xv2 = xr[k4 * 4 + 2], xv3 = xr[k4 * 4 + 3];
      gr = fmaf(wa.x, xv0, gr); gr = fmaf(wa.y, xv1, gr);
      gr = fmaf(wa.z, xv2, gr); gr = fmaf(wa.w, xv3, gr);
      gz = fmaf(wb.x, xv0, gz); gz = fmaf(wb.y, xv1, gz);
      gz = fmaf(wb.z, xv2, gz); gz = fmaf(wb.w, xv3, gz);
      gin = fmaf(wc.x, xv0, gin); gin = fmaf(wc.y, xv1, gin);
      gin = fmaf(wc.z, xv2, gin); gin = fmaf(wc.w, xv3, gin);
    }
  }
  for (int t0 = 0; t0 < 512; t0 += 256) {
    __syncthreads();
    stage(hprev, 512, t0, tid, xsh);
    __syncthreads();
    const float4* w0p = (const float4*)(w_hh + (size_t)j * 512 + t0 + kb);
    const float4* w1p = (const float4*)(w_hh + (size_t)(j + 512) * 512 + t0 + kb);
    const float4* w2p = (const float4*)(w_hh + (size_t)(j + 1024) * 512 + t0 + kb);
    const float* xr = xsh + b * 257 + kb;
#pragma unroll 4
    for (int k4 = 0; k4 < 16; k4++) {
      float4 wa = w0p[k4], wb = w1p[k4], wc = w2p[k4];
      float xv0 = xr[k4 * 4 + 0], xv1 = xr[k4 * 4 + 1];
      float xv2 = xr[k4 * 4 + 2], xv3 = xr[k4 * 4 + 3];
      gr = fmaf(wa.x, xv0, gr); gr = fmaf(wa.y, xv1, gr);
      gr = fmaf(wa.z, xv2, gr); gr = fmaf(wa.w, xv3, gr);
      gz = fmaf(wb.x, xv0, gz); gz = fmaf(wb.y, xv1, gz);
      gz = fmaf(wb.z, xv2, gz); gz = fmaf(wb.w, xv3, gz);
      ghn = fmaf(wc.x, xv0, ghn); ghn = fmaf(wc.y, xv1, ghn);
      ghn = fmaf(wc.z, xv2, ghn); ghn = fmaf(wc.w, xv3, ghn);
    }
  }
  red[tid * 4 + 0] = gr;
  red[tid * 4 + 1] = gz;
  red[tid * 4 + 2] = gin;
  red[tid * 4 + 3] = ghn;
  __syncthreads();
  if (tid < 64) {
#pragma unroll
    for (int g = 1; g < 4; g++) {
      gr += red[(tid + g * 64) * 4 + 0];
      gz += red[(tid + g * 64) * 4 + 1];
      gin += red[(tid + g * 64) * 4 + 2];
      ghn += red[(tid + g * 64) * 4 + 3];
    }
    gr += b_ih[j] + b_hh[j];
    gz += b_ih[j + 512] + b_hh[j + 512];
    gin += b_ih[j + 1024];
    ghn += b_hh[j + 1024];
    float r = 1.f / (1.f + __expf(-gr));
    float zz = 1.f / (1.f + __expf(-gz));
    float nv = gin + r * ghn;
    float e2 = __expf(-2.f * fabsf(nv));
    float th = (1.f - e2) / (1.f + e2);
    th = copysignf(th, nv);
    float hp = hprev[b * 512 + j];  // staged this step -> fresh in L1/L2
    float hn = (1.f - zz) * th + zz * hp;
    st_f32_coh(hout + b * 512 + j, hn);
    if (states) states[(size_t)(srow + b) * 1536 + j] = f2bf(hn);
  }
}

// Persistent kernel: prologue + all 63 decode steps in ONE launch.
// grid=256 (1 wg/CU, 4x resource slack -> co-residency guaranteed), 256 threads.
__global__ __launch_bounds__(256, 1) void k_steps(StepParams p) {
  __shared__ float xsh[32 * 257];  // 32.9 KB: gru x-stage; reused as encwt esh
  __shared__ float red[1024];
  __shared__ float h1sh[512];
  __shared__ float ssh[128];
  __shared__ float red2[128];
  int tid = threadIdx.x;
  int w = blockIdx.x;

  // ---------------- prologue (init h slot 0, enc->bf16, encwt) --------------
  // All prologue writes use sc0sc1 write-through: no dirty L2 lines anywhere,
  // so any XCD's later cached read fills fresh from MALL.
  {
    int idx = w * 256 + tid;
    if (idx < 16384) st_f32_coh(p.h0buf + idx, p.hidden[idx]);
    else if (idx < 32768) st_f32_coh(p.h1buf + (idx - 16384), p.hidden[idx]);
    for (int r = 0; r < 16; r++) {
      size_t i4 = (size_t)r * 65536 + idx;
      float4 v = *(const float4*)(p.enc + i4 * 4);
      ushort4 o;
      o.x = f2bf(v.x); o.y = f2bf(v.y); o.z = f2bf(v.z); o.w = f2bf(v.w);
      union { ushort4 u; i32x2 d; } cv;
      cv.u = o;
      st_b64_coh(p.encb + i4 * 4, cv.d);
    }
    // encwt (TRANSPOSED [b][s][h]): this wg does virtual blocks w and w+256
    for (int blk = w; blk < 512; blk += 256) {
      int b = blk >> 4, s0 = (blk & 15) * 8;
      __syncthreads();
      for (int u = 0; u < 32; u++) {
        int f = u * 256 + tid;
        xsh[f] = p.enc[((size_t)b * 128 + s0 + (f >> 10)) * 1024 + (f & 1023)];
      }
      __syncthreads();
      float acc0[8] = {}, acc1[8] = {};
      for (int e = 0; e < 1024; e++) {
        float w0 = p.Wa[e * 512 + tid];
        float w1 = p.Wa[e * 512 + tid + 256];
#pragma unroll
        for (int si = 0; si < 8; si++) {
          float ev = xsh[si * 1024 + e];
          acc0[si] += w0 * ev;
          acc1[si] += w1 * ev;
        }
      }
#pragma unroll
      for (int si = 0; si < 8; si++) {
        st_u16_coh(p.encwt + ((size_t)b * 128 + s0 + si) * 512 + tid, f2bf(acc0[si]));
        st_u16_coh(p.encwt + ((size_t)b * 128 + s0 + si) * 512 + tid + 256, f2bf(acc1[si]));
      }
    }
  }
  unsigned int* bar = p.bars;
  gbar(bar++);

  // XCD-aware roles: wg->XCD is w%8; give each XCD 4 whole batches so its L2
  // working set (encwt 512K + encb 1M + GRU rows 1.2M) fits in 4 MB.
  int xcd = w & 7, loc = w >> 3;
  int ab = xcd * 4 + (loc >> 3);  // batch
  int ec = loc & 7;               // e/emb chunk
  for (int t = 0; t < 63; t++) {
    const float* h1prev = p.h1buf + (size_t)t * 16384;
    float* x0t = p.x0b + (size_t)t * 49152;
    // ---------------- Phase A: attention ----------------
    {
      float2 hv = *(const float2*)(h1prev + ab * 512 + tid * 2);
      h1sh[tid * 2] = hv.x;
      h1sh[tid * 2 + 1] = hv.y;
    }
    __syncthreads();
    {  // scores: 2 threads per s (h halves), bf16x8 loads from transposed encwt
      int s = tid & 127, part = tid >> 7;
      const unsigned short* ew = p.encwt + ((size_t)ab * 128 + s) * 512 + part * 256;
      const float* hh = h1sh + part * 256;
      float pacc = 0.f;
#pragma unroll 8
      for (int hc = 0; hc < 32; hc++) {
        bf16x8 v = *(const bf16x8*)(ew + hc * 8);
        const float* h8 = hh + hc * 8;
        pacc += bf2f((unsigned short)v[0]) * h8[0] + bf2f((unsigned short)v[1]) * h8[1]
              + bf2f((unsigned short)v[2]) * h8[2] + bf2f((unsigned short)v[3]) * h8[3]
              + bf2f((unsigned short)v[4]) * h8[4] + bf2f((unsigned short)v[5]) * h8[5]
              + bf2f((unsigned short)v[6]) * h8[6] + bf2f((unsigned short)v[7]) * h8[7];
      }
      red[tid] = pacc;
    }
    __syncthreads();
    if (tid < 128) {
      float sc = (red[tid] + red[tid + 128]) * 0.03125f;  // 1/sqrt(1024)
      if (p.mask[ab * 128 + tid] == 0) sc = -__builtin_huge_valf();
      ssh[tid] = sc;
      red2[tid] = sc;
    }
    __syncthreads();
    for (int st = 64; st > 0; st >>= 1) {
      if (tid < st) red2[tid] = fmaxf(red2[tid], red2[tid + st]);
      __syncthreads();
    }
    float mx = red2[0];
    __syncthreads();
    if (tid < 128) {
      float e = __expf(ssh[tid] - mx);
      ssh[tid] = e;
      red2[tid] = e;
    }
    __syncthreads();
    for (int st = 64; st > 0; st >>= 1) {
      if (tid < st) red2[tid] += red2[tid + st];
      __syncthreads();
    }
    float inv = 1.f / red2[0];
    __syncthreads();
    if (tid < 128) ssh[tid] *= inv;
    __syncthreads();
    {  // ctx for this wg's 128-wide e-chunk (2 threads per e, s halves)
      int el = tid & 127, sh_ = tid >> 7;
      const unsigned short* eb = p.encb + (size_t)ab * 131072 + ec * 128 + el;
      int sbase = sh_ * 64;
      float c = 0.f;
#pragma unroll 8
      for (int s2 = 0; s2 < 64; s2++)
        c += ssh[sbase + s2] * bf2f(eb[(size_t)(sbase + s2) * 1024]);
      red[tid] = c;
    }
    __syncthreads();
    if (tid < 128) {
      float cv = red[tid] + red[tid + 128];
      st_f32_coh(x0t + ab * 1536 + 512 + ec * 128 + tid, cv);
      p.states[(size_t)(t * 32 + ab) * 1536 + 512 + ec * 128 + tid] = f2bf(cv);
    }
    {  // embedding gather: this wg's 64-wide chunk
      int tok = p.tgt[ab * 64 + t];
      if (tid < 64)
        st_f32_coh(x0t + ab * 1536 + ec * 64 + tid,
                   p.embedding[(size_t)tok * 512 + ec * 64 + tid]);
    }
    gbar(bar++);
    // ---------------- Phase B: GRU layer 0 ----------------
    gru_phase(x0t, 1536, p.h0buf + (size_t)t * 16384, p.w_ih0, p.w_hh0, p.b_ih0,
              p.b_hh0, p.h0buf + (size_t)(t + 1) * 16384,
              (unsigned short*)nullptr, 0, w, tid, xsh, red);
    gbar(bar++);
    // ---------------- Phase C: GRU layer 1 ----------------
    gru_phase(p.h0buf + (size_t)(t + 1) * 16384, 512, p.h1buf + (size_t)t * 16384,
              p.w_ih1, p.w_hh1, p.b_ih1, p.b_hh1,
              p.h1buf + (size_t)(t + 1) * 16384, p.states, t * 32, w, tid, xsh, red);
    gbar(bar++);
  }
}

// ---------------- fc_w fp32 -> bf16 one-time convert (guarded on ws_size) ---
__global__ __launch_bounds__(256) void k_cvt_fcw(const float* __restrict__ w,
                                                 unsigned short* __restrict__ o) {
  size_t i = ((size_t)blockIdx.x * 256 + threadIdx.x) * 8;
  float4 a = *(const float4*)(w + i);
  float4 b = *(const float4*)(w + i + 4);
  ushort4 lo, hi;
  lo.x = f2bf(a.x); lo.y = f2bf(a.y); lo.z = f2bf(a.z); lo.w = f2bf(a.w);
  hi.x = f2bf(b.x); hi.y = f2bf(b.y); hi.z = f2bf(b.z); hi.w = f2bf(b.w);
  *(ushort4*)(o + i) = lo;
  *(ushort4*)(o + i + 4) = hi;
}

// ---------------- batched logits GEMM: [2016x1536] @ fc_w.T [1536x32000] ----
// XCD-swizzled: the 16 m-blocks sharing one B-panel land on one XCD's L2.
template <bool PRE>
__global__ __launch_bounds__(256) void k_gemm(
    const unsigned short* __restrict__ states,  // [2048][1536] bf16
    const float* __restrict__ fc_w,             // [32000][1536]
    const unsigned short* __restrict__ fcwb,    // [32000][1536] bf16 (PRE only)
    const float* __restrict__ fc_b,             // [32000]
    float* __restrict__ out) {                  // [32][63][32000]
  __shared__ unsigned short Ash[128 * 40];
  __shared__ unsigned short Bsh[128 * 40];
  int tid = threadIdx.x;
  int bx = blockIdx.x;
  int bid = (bx & 7) * 500 + (bx >> 3);  // 4000 = 8 XCDs * 500, bijective
  int m0 = (bid & 15) * 128;
  int n0 = (bid >> 4) * 128;
  int lane = tid & 63, wave = tid >> 6;
  int q = lane >> 4, l16 = lane & 15;
  int wrow = (wave >> 1) * 64, wcol = (wave & 1) * 64;
  int arow = tid >> 1, ahalf = tid & 1;
  f32x4 acc[4][4] = {};
  const unsigned short* ag = states + (size_t)(m0 + arow) * 1536 + ahalf * 16;
  const float* bg = fc_w + (size_t)(n0 + arow) * 1536 + ahalf * 16;
  const unsigned short* bgb = PRE ? fcwb + (size_t)(n0 + arow) * 1536 + ahalf * 16 : nullptr;
  for (int k0 = 0; k0 < 1536; k0 += 32) {
    {  // stage A (already bf16)
      const int4* src = (const int4*)(ag + k0);
      int4* dst = (int4*)(Ash + arow * 40 + ahalf * 16);
      dst[0] = src[0];
      dst[1] = src[1];
    }
    if constexpr (PRE) {  // stage B (pre-converted bf16)
      const int4* src = (const int4*)(bgb + k0);
      int4* dst = (int4*)(Bsh + arow * 40 + ahalf * 16);
      dst[0] = src[0];
      dst[1] = src[1];
    } else {  // stage B (fp32 -> bf16)
      const float4* src = (const float4*)(bg + k0);
      __align__(16) unsigned short us[16];
#pragma unroll
      for (int i = 0; i < 4; i++) {
        float4 v = src[i];
        us[i * 4 + 0] = f2bf(v.x);
        us[i * 4 + 1] = f2bf(v.y);
        us[i * 4 + 2] = f2bf(v.z);
        us[i * 4 + 3] = f2bf(v.w);
      }
      int4* dst = (int4*)(Bsh + arow * 40 + ahalf * 16);
      dst[0] = ((int4*)us)[0];
      dst[1] = ((int4*)us)[1];
    }
    __syncthreads();
    bf16x8 av[4], bv[4];
#pragma unroll
    for (int i = 0; i < 4; i++) {
      av[i] = *(const bf16x8*)(Ash + (wrow + i * 16 + l16) * 40 + q * 8);
      bv[i] = *(const bf16x8*)(Bsh + (wcol + i * 16 + l16) * 40 + q * 8);
    }
#pragma unroll
    for (int mi = 0; mi < 4; mi++)
#pragma unroll
      for (int ni = 0; ni < 4; ni++)
        acc[mi][ni] = __builtin_amdgcn_mfma_f32_16x16x32_bf16(av[mi], bv[ni], acc[mi][ni], 0, 0, 0);
    __syncthreads();
  }
  float fb[4];
#pragma unroll
  for (int ni = 0; ni < 4; ni++) fb[ni] = fc_b[n0 + wcol + ni * 16 + l16];
#pragma unroll
  for (int mi = 0; mi < 4; mi++) {
#pragma unroll
    for (int r = 0; r < 4; r++) {
      int grow = m0 + wrow + mi * 16 + q * 4 + r;
      if (grow < 2016) {
        int tt = grow >> 5, bb = grow & 31;
        float* op = out + (size_t)bb * 2016000 + (size_t)tt * 32000 + n0 + wcol;
#pragma unroll
        for (int ni = 0; ni < 4; ni++)
          op[ni * 16 + l16] = acc[mi][ni][r] + fb[ni];
      }
    }
  }
}

extern "C" void kernel_launch(void* const* d_in, const int* in_sizes, int n_in,
                              void* d_out, int out_size, void* d_ws, size_t ws_size,
                              hipStream_t stream) {
  const int* tgt = (const int*)d_in[0];
  const float* hidden = (const float*)d_in[1];
  const float* enc = (const float*)d_in[2];
  const int* mask = (const int*)d_in[3];
  const float* embedding = (const float*)d_in[4];
  const float* Wa = (const float*)d_in[5];
  const float* w_ih0 = (const float*)d_in[6];
  const float* w_hh0 = (const float*)d_in[7];
  const float* b_ih0 = (const float*)d_in[8];
  const float* b_hh0 = (const float*)d_in[9];
  const float* w_ih1 = (const float*)d_in[10];
  const float* w_hh1 = (const float*)d_in[11];
  const float* b_ih1 = (const float*)d_in[12];
  const float* b_hh1 = (const float*)d_in[13];
  const float* fc_w = (const float*)d_in[14];
  const float* fc_b = (const float*)d_in[15];
  float* out = (float*)d_out;
  char* ws = (char*)d_ws;

  float* h0buf = (float*)(ws + 0);                           // [64][32][512] f32 slots
  float* h1buf = (float*)(ws + 4194304);                     // [64][32][512] f32 slots
  float* x0b = (float*)(ws + 8388608);                       // [63][32][1536] f32 slots
  unsigned short* encb = (unsigned short*)(ws + 20774912);   // [32][128][1024] bf16
  unsigned short* encwt = (unsigned short*)(ws + 29163520);  // [32][128][512] bf16
  unsigned short* states = (unsigned short*)(ws + 33357824); // [2048][1536] bf16
  unsigned int* bars = (unsigned int*)(ws + 39649280);       // 190 counters
  const size_t FCWB_OFF = 41943040ull;
  unsigned short* fcwb = (unsigned short*)(ws + FCWB_OFF);   // [32000][1536] bf16
  bool pre = ws_size >= FCWB_OFF + 98304000ull;

  hipMemsetAsync(bars, 0, 4096, stream);
  if (pre) k_cvt_fcw<<<24000, 256, 0, stream>>>(fc_w, fcwb);

  StepParams p;
  p.tgt = tgt; p.mask = mask; p.embedding = embedding; p.enc = enc; p.Wa = Wa;
  p.hidden = hidden;
  p.w_ih0 = w_ih0; p.w_hh0 = w_hh0; p.b_ih0 = b_ih0; p.b_hh0 = b_hh0;
  p.w_ih1 = w_ih1; p.w_hh1 = w_hh1; p.b_ih1 = b_ih1; p.b_hh1 = b_hh1;
  p.h0buf = h0buf; p.h1buf = h1buf; p.x0b = x0b;
  p.encb = encb; p.encwt = encwt; p.states = states; p.bars = bars;

  k_steps<<<dim3(256), dim3(256), 0, stream>>>(p);

  if (pre) k_gemm<true><<<4000, 256, 0, stream>>>(states, fc_w, fcwb, fc_b, out);
  else k_gemm<false><<<4000, 256, 0, stream>>>(states, fc_w, nullptr, fc_b, out);
}